// Round 13
// baseline (2177.599 us; speedup 1.0000x reference)
//
#include <hip/hip_runtime.h>

#define B_ 64
#define S_ 512
#define D_ 256
#define H_ 512

typedef __attribute__((ext_vector_type(8))) short bfx8;
typedef __attribute__((ext_vector_type(4))) float f32x4;

#define MFMA16(a,b,c) __builtin_amdgcn_mfma_f32_16x16x32_bf16((a),(b),(c),0,0,0)
#define AL(p)  __hip_atomic_load((p), __ATOMIC_RELAXED, __HIP_MEMORY_SCOPE_AGENT)

__device__ __forceinline__ unsigned short f2bf(float x){
  union { float f; unsigned int u; } v; v.f = x;
  unsigned int r = v.u + 0x7fffu + ((v.u >> 16) & 1u);
  return (unsigned short)(r >> 16);
}
__device__ __forceinline__ float bf2f(unsigned short b){
  union { unsigned int u; float f; } v; v.u = ((unsigned int)b) << 16; return v.f;
}
__device__ __forceinline__ float sigm(float x){ return 1.f/(1.f + __expf(-x)); }
__device__ __forceinline__ float tanhfast(float x){
  float xc = fminf(fmaxf(x, -15.f), 15.f);
  float e = __expf(2.f * xc);
  return (e - 1.f) / (e + 1.f);
}
__device__ __forceinline__ void unpack8(uint4 a, uint4 b, bfx8& hi, bfx8& lo){
  hi[0]=(short)(a.x>>16); lo[0]=(short)(a.x&0xffffu);
  hi[1]=(short)(a.y>>16); lo[1]=(short)(a.y&0xffffu);
  hi[2]=(short)(a.z>>16); lo[2]=(short)(a.z&0xffffu);
  hi[3]=(short)(a.w>>16); lo[3]=(short)(a.w&0xffffu);
  hi[4]=(short)(b.x>>16); lo[4]=(short)(b.x&0xffffu);
  hi[5]=(short)(b.y>>16); lo[5]=(short)(b.y&0xffffu);
  hi[6]=(short)(b.z>>16); lo[6]=(short)(b.z&0xffffu);
  hi[7]=(short)(b.w>>16); lo[7]=(short)(b.w&0xffffu);
}
__device__ __forceinline__ void cvt8(const float* vv, bfx8& hi, bfx8& lo){
  #pragma unroll
  for (int j = 0; j < 8; ++j) {
    unsigned short h = f2bf(vv[j]);
    hi[j] = (short)h;
    lo[j] = (short)f2bf(vv[j] - bf2f(h));
  }
}

// ---------------- prep: x fragments [t][q][kt(8)][lane(64)][8] hi/lo ----------------
__global__ void __launch_bounds__(256) k_xfrag(const float* __restrict__ x,
                                               unsigned short* __restrict__ xhi,
                                               unsigned short* __restrict__ xlo){
  int idx = blockIdx.x*256 + threadIdx.x;            // 2^20 threads
  int lane = idx & 63, kt = (idx>>6)&7, q = (idx>>9)&3, t = idx>>11;
  int b = q*16 + (lane&15);
  int k0 = kt*32 + ((lane>>4)&3)*8;
  const float4* p = (const float4*)(x + ((size_t)b*S_ + t)*D_ + k0);
  float4 v0 = p[0], v1 = p[1];
  float vv[8] = {v0.x,v0.y,v0.z,v0.w,v1.x,v1.y,v1.z,v1.w};
  bfx8 hi, lo; cvt8(vv, hi, lo);
  *(bfx8*)(xhi + (size_t)idx*8) = hi;
  *(bfx8*)(xlo + (size_t)idx*8) = lo;
}

// ---------------- prep: Wih fragments [dir][q][r(32)][kt(8)][nt(4)][lane(64)][8] ----------------
__global__ void __launch_bounds__(256) k_wfrag(const float* __restrict__ fWih,
                                               const float* __restrict__ bWih,
                                               unsigned short* __restrict__ whi,
                                               unsigned short* __restrict__ wlo){
  int idx = blockIdx.x*256 + threadIdx.x;            // 2^19 threads
  int lane = idx & 63, nt = (idx>>6)&3, kt = (idx>>8)&7, r = (idx>>11)&31, dir = (idx>>18)&1;
  int row = nt*512 + r*16 + (lane&15);
  int k0 = kt*32 + ((lane>>4)&3)*8;
  const float* W = dir ? bWih : fWih;
  const float4* p = (const float4*)(W + (size_t)row*D_ + k0);
  float4 v0 = p[0], v1 = p[1];
  float vv[8] = {v0.x,v0.y,v0.z,v0.w,v1.x,v1.y,v1.z,v1.w};
  bfx8 hi, lo; cvt8(vv, hi, lo);
  *(bfx8*)(whi + (size_t)idx*8) = hi;
  *(bfx8*)(wlo + (size_t)idx*8) = lo;
}

// ---------------- prep: att_W fragments [nt(4)][kt(32)][lane(64)][8] ----------------
__global__ void __launch_bounds__(256) k_awfrag(const float* __restrict__ attW,
                                                unsigned short* __restrict__ awhi,
                                                unsigned short* __restrict__ awlo){
  int idx = blockIdx.x*256 + threadIdx.x;            // 8192 threads
  int lane = idx & 63, kt = (idx>>6)&31, nt = idx>>11;
  int n = nt*16 + (lane&15);
  int k0 = kt*32 + ((lane>>4)&3)*8;
  const float4* p = (const float4*)(attW + (size_t)n*1024 + k0);
  float4 v0 = p[0], v1 = p[1];
  float vv[8] = {v0.x,v0.y,v0.z,v0.w,v1.x,v1.y,v1.z,v1.w};
  bfx8 hi, lo; cvt8(vv, hi, lo);
  *(bfx8*)(awhi + (size_t)idx*8) = hi;
  *(bfx8*)(awlo + (size_t)idx*8) = lo;
}

// ---------------- main recurrence: 256 WGs = 8 groups(dir x quarter) x 32 col-WGs ----------------
// R12 + EPOCH-TAGGED DATA POLLING (no digest): each h word in the rotating hx exchange
// carries a 2-bit step tag (ti&3) stolen from the lo-half LSBs (history hpk copy stays
// full precision). Consumers issue the 16 bulk loads at loop top (overlap the x-part) and
// validate per word: tag==(ti-1)&3 && hh!=0xFFFF; re-issue only invalid words. Detection
// and transfer are now the same memory op.
// Safety: mod-4 tag distinguishes step t-1 from t-3 (depth-2 rotation); end-of-step
// s_waitcnt vmcnt(0) orders each thread's stores across steps (no stale-by-4); per-launch
// memset(0xFF) of hx kills cross-replay staleness (hh=0xFFFF is an impossible bf16 for
// |h|<1 -> always rejected).
__global__ void __launch_bounds__(256,1) k_lstm(
    const float* __restrict__ fWhh, const float* __restrict__ bWhh,
    const float* __restrict__ fbih, const float* __restrict__ fbhh,
    const float* __restrict__ bbih, const float* __restrict__ bbhh,
    unsigned int* __restrict__ hpk,          // 128 MB history (plain stores, attention input)
    unsigned int* __restrict__ hx,           // 512 KB rotating exchange (atomic, tagged)
    const unsigned short* __restrict__ xhi, const unsigned short* __restrict__ xlo,
    const unsigned short* __restrict__ whi, const unsigned short* __restrict__ wlo)
{
  extern __shared__ char smem[];
  unsigned short* shh   = (unsigned short*)smem;            // Whh hi frags kt0..9 = 40960 B
  unsigned short* shl   = shh + 20480;                      // Whh lo frags kt0..9 = 40960 B
  unsigned short* sh_hi = (unsigned short*)(smem + 81920);  // staged h hi [kt16][lane64][8] = 16 KB
  unsigned short* sh_lo = sh_hi + 8192;                     // staged h lo = 16 KB
  float* gbuf = (float*)(smem + 114688);                    // gate exchange [4][16][16] = 4 KB
  char*  xbuf = smem + 118784;                              // x frags ping-pong 2 x 16 KB

  const int tid = threadIdx.x, bid = blockIdx.x;
  const int g = bid & 7, r = bid >> 3;
  const int dir = g >> 2, q = g & 3;
  const int wv = tid >> 6, lane = tid & 63;
  const float* Whh = dir ? bWhh : fWhh;

  // stage Whh slice: kt 0..9 -> LDS fragments; kt 10..15 -> registers
  bfx8 rbh[6], rbl[6];
  #pragma unroll
  for (int i = 0; i < 16; ++i) {
    int fl = tid & 63, fnt = (tid>>6)&3;
    int row = fnt*512 + r*16 + (fl&15);
    int k0 = i*32 + ((fl>>4)&3)*8;
    const float4* p = (const float4*)(Whh + (size_t)row*H_ + k0);
    float4 v0 = p[0], v1 = p[1];
    float vv[8] = {v0.x,v0.y,v0.z,v0.w,v1.x,v1.y,v1.z,v1.w};
    bfx8 hi, lo; cvt8(vv, hi, lo);
    if (i < 10) {
      *(bfx8*)(shh + (size_t)((i*4+fnt)*64+fl)*8) = hi;
      *(bfx8*)(shl + (size_t)((i*4+fnt)*64+fl)*8) = lo;
    } else { rbh[i-10] = hi; rbl[i-10] = lo; }
  }

  // Wih fragments -> registers (constant across steps)
  bfx8 wrh[8], wrl[8];
  {
    const size_t wb = (((size_t)(dir*4+q)*32 + r)*32 + wv)*64;
    #pragma unroll
    for (int kt = 0; kt < 8; ++kt) {
      wrh[kt] = *(const bfx8*)(whi + (wb + kt*256 + lane)*8);
      wrl[kt] = *(const bfx8*)(wlo + (wb + kt*256 + lane)*8);
    }
  }

  const int b_l = tid >> 4, cc = tid & 15;
  const int jcol = r*16 + cc;
  const float* bih = dir ? bbih : fbih;
  const float* bhh = dir ? bbhh : fbhh;
  float bias[4];
  #pragma unroll
  for (int gt = 0; gt < 4; ++gt) bias[gt] = bih[gt*512 + jcol] + bhh[gt*512 + jcol];
  float cst = 0.f;
  const int hkt   = jcol >> 5;
  const int hlane = ((jcol>>3)&3)*16 + b_l;
  const int hj    = jcol & 7;

  { // prologue: preload step-0 x block into xbuf[0]
    const int t0 = dir ? (S_-1) : 0;
    const char* hsrc = (const char*)(xhi + (((size_t)t0*4+q) << 12));
    const char* lsrc = (const char*)(xlo + (((size_t)t0*4+q) << 12));
    *(uint4*)(xbuf + tid*16)          = *(const uint4*)(hsrc + tid*16);
    *(uint4*)(xbuf + 4096 + tid*16)   = *(const uint4*)(hsrc + 4096 + tid*16);
    *(uint4*)(xbuf + 8192 + tid*16)   = *(const uint4*)(lsrc + tid*16);
    *(uint4*)(xbuf + 12288 + tid*16)  = *(const uint4*)(lsrc + 4096 + tid*16);
  }
  __syncthreads();

  for (int ti = 0; ti < S_; ++ti) {
    const int t = dir ? (S_-1-ti) : ti;
    char* xb  = xbuf + ((ti)&1)*16384;
    char* xbn = xbuf + ((ti+1)&1)*16384;
    f32x4 a0 = {0.f,0.f,0.f,0.f}, a1 = a0, a2 = a0, a3 = a0, a4 = a0, a5 = a0;

    // ---- issue the bulk h polls EARLY: the data IS the ready signal ----
    unsigned long long qs[16];
    const unsigned long long* sp = nullptr;
    const unsigned expt = (unsigned)((ti-1) & 3);
    if (ti > 0) {
      sp = (const unsigned long long*)(hx + ((((size_t)(dir*4 + q))*2 + ((ti-1)&1)) << 13));
      #pragma unroll
      for (int i = 0; i < 16; ++i) qs[i] = AL(sp + i*256 + tid);
    }

    // ---- issue next step's x-block loads (land under the h-poll/x-MFMA) ----
    uint4 xr0, xr1, xr2, xr3;
    const bool pf = (ti + 1 < S_);
    if (pf) {
      const int tn = dir ? (S_-1-(ti+1)) : (ti+1);
      const char* hsrc = (const char*)(xhi + (((size_t)tn*4+q) << 12));
      const char* lsrc = (const char*)(xlo + (((size_t)tn*4+q) << 12));
      xr0 = *(const uint4*)(hsrc + tid*16);
      xr1 = *(const uint4*)(hsrc + 4096 + tid*16);
      xr2 = *(const uint4*)(lsrc + tid*16);
      xr3 = *(const uint4*)(lsrc + 4096 + tid*16);
    }

    { // input projection from LDS (h-independent) — overlaps the in-flight h polls
      const unsigned short* xh = (const unsigned short*)xb;
      const unsigned short* xl = (const unsigned short*)(xb + 8192);
      #pragma unroll
      for (int kt = 0; kt < 8; ++kt) {
        bfx8 x0 = *(const bfx8*)(xh + (size_t)(kt*64+lane)*8);
        bfx8 x1 = *(const bfx8*)(xl + (size_t)(kt*64+lane)*8);
        if (kt & 1) {
          a3 = MFMA16(x0, wrh[kt], a3); a4 = MFMA16(x0, wrl[kt], a4); a5 = MFMA16(x1, wrh[kt], a5);
        } else {
          a0 = MFMA16(x0, wrh[kt], a0); a1 = MFMA16(x0, wrl[kt], a1); a2 = MFMA16(x1, wrh[kt], a2);
        }
      }
    }

    if (ti > 0) {
      // ---- validate tagged words; re-issue only invalid ones ----
      for (;;) {
        bool ok = true;
        #pragma unroll
        for (int i = 0; i < 16; ++i) {
          unsigned lo32 = (unsigned)qs[i], hi32 = (unsigned)(qs[i] >> 32);
          ok &= ((lo32 >> 16) != 0xFFFFu) & ((lo32 & 3u) == expt)
              & ((hi32 >> 16) != 0xFFFFu) & ((hi32 & 3u) == expt);
        }
        if (ok) break;
        #pragma unroll
        for (int i = 0; i < 16; ++i) {
          unsigned lo32 = (unsigned)qs[i], hi32 = (unsigned)(qs[i] >> 32);
          bool v = ((lo32 >> 16) != 0xFFFFu) & ((lo32 & 3u) == expt)
                 & ((hi32 >> 16) != 0xFFFFu) & ((hi32 & 3u) == expt);
          if (!v) qs[i] = AL(sp + i*256 + tid);
        }
      }
      // ---- stage to LDS (hi/lo planes; tag bits masked out of lo) ----
      #pragma unroll
      for (int i = 0; i < 16; ++i) {
        unsigned int e0 = (unsigned int)qs[i], e1 = (unsigned int)(qs[i] >> 32);
        *(unsigned int*)(sh_hi + i*512 + tid*2) = (e0 >> 16)      | (e1 & 0xFFFF0000u);
        *(unsigned int*)(sh_lo + i*512 + tid*2) = (e0 & 0xFFFCu)  | ((e1 << 16) & 0xFFFC0000u);
      }
    }
    // ---- write the prefetched x-block into the other ping-pong half ----
    if (pf) {
      *(uint4*)(xbn + tid*16)         = xr0;
      *(uint4*)(xbn + 4096 + tid*16)  = xr1;
      *(uint4*)(xbn + 8192 + tid*16)  = xr2;
      *(uint4*)(xbn + 12288 + tid*16) = xr3;
    }
    __syncthreads();               // barB: stage + xbuf visible
    if (ti > 0) {
      #pragma unroll
      for (int kt = 0; kt < 16; ++kt) {
        bfx8 ah = *(const bfx8*)(sh_hi + kt*512 + lane*8);
        bfx8 al = *(const bfx8*)(sh_lo + kt*512 + lane*8);
        bfx8 bh, bl;
        if (kt < 10) {
          bh = *(const bfx8*)(shh + (size_t)((kt*4+wv)*64 + lane)*8);
          bl = *(const bfx8*)(shl + (size_t)((kt*4+wv)*64 + lane)*8);
        } else { bh = rbh[kt-10]; bl = rbl[kt-10]; }
        if (kt & 1) {
          a3 = MFMA16(ah, bh, a3); a4 = MFMA16(ah, bl, a4); a5 = MFMA16(al, bh, a5);
        } else {
          a0 = MFMA16(ah, bh, a0); a1 = MFMA16(ah, bl, a1); a2 = MFMA16(al, bh, a2);
        }
      }
    }

    f32x4 gate = (a0 + a1) + (a2 + a3) + (a4 + a5);
    #pragma unroll
    for (int rr = 0; rr < 4; ++rr)
      gbuf[wv*256 + (((lane>>4)&3)*4+rr)*16 + (lane&15)] = gate[rr];
    __syncthreads();               // barD: gbuf visible
    {
      float gi = gbuf[0*256 + b_l*16 + cc] + bias[0];
      float gf = gbuf[1*256 + b_l*16 + cc] + bias[1];
      float gg = gbuf[2*256 + b_l*16 + cc] + bias[2];
      float go = gbuf[3*256 + b_l*16 + cc] + bias[3];
      float is = sigm(gi), fs = sigm(gf), gs = tanhfast(gg), os = tanhfast(go);
      os = sigm(go);
      cst = fs*cst + is*gs;
      float hv = os * tanhfast(cst);
      unsigned short hh = f2bf(hv);
      unsigned short hl = f2bf(hv - bf2f(hh));
      unsigned int pk  = (((unsigned int)hh) << 16) | (unsigned int)hl;
      unsigned int pkt = (((unsigned int)hh) << 16) | ((unsigned int)hl & 0xFFFCu)
                       | ((unsigned int)ti & 3u);
      size_t hoff = (size_t)hkt*512 + hlane*8 + hj;
      hpk[((((size_t)dir*S_ + t)*4 + q) << 13) + hoff] = pk;               // history (untagged)
      __hip_atomic_store(hx + ((((size_t)(dir*4 + q))*2 + (ti&1)) << 13) + hoff, pkt,
                         __ATOMIC_RELAXED, __HIP_MEMORY_SCOPE_AGENT);      // exchange (tagged)
    }
    // order this thread's stores across steps (prevents stale-by-4 tag aliasing)
    asm volatile("s_waitcnt vmcnt(0)" ::: "memory");
  }
}

// ---------------- attention scores: one WG per s ----------------
__global__ void __launch_bounds__(256) k_att1(const unsigned int* __restrict__ hpk,
                                              const unsigned short* __restrict__ awhi,
                                              const unsigned short* __restrict__ awlo,
                                              const float* __restrict__ attv,
                                              float* __restrict__ attbuf){
  const int s = blockIdx.x;
  const int tid = threadIdx.x, wv = tid >> 6, lane = tid & 63;
  const int q = wv;
  f32x4 z = {0.f,0.f,0.f,0.f};
  f32x4 acc[4][3];
  #pragma unroll
  for (int nt = 0; nt < 4; ++nt) { acc[nt][0] = z; acc[nt][1] = z; acc[nt][2] = z; }
  for (int kt = 0; kt < 32; ++kt) {
    int dir = kt >> 4, ktt = kt & 15;
    const unsigned int* hb = hpk + ((((size_t)dir*S_ + s)*4 + q) << 13) + ktt*512 + lane*8;
    uint4 u0 = *(const uint4*)hb, u1 = *(const uint4*)(hb + 4);
    bfx8 ah, al; unpack8(u0, u1, ah, al);
    #pragma unroll
    for (int nt = 0; nt < 4; ++nt) {
      bfx8 bh = *(const bfx8*)(awhi + (size_t)((nt*32+kt)*64+lane)*8);
      bfx8 bl = *(const bfx8*)(awlo + (size_t)((nt*32+kt)*64+lane)*8);
      acc[nt][0] = MFMA16(ah, bh, acc[nt][0]);
      acc[nt][1] = MFMA16(ah, bl, acc[nt][1]);
      acc[nt][2] = MFMA16(al, bh, acc[nt][2]);
    }
  }
  float part[4] = {0.f,0.f,0.f,0.f};
  #pragma unroll
  for (int nt = 0; nt < 4; ++nt) {
    f32x4 d = (acc[nt][0] + acc[nt][1]) + acc[nt][2];
    float vvv = attv[nt*16 + (lane&15)];
    #pragma unroll
    for (int rr = 0; rr < 4; ++rr) part[rr] += tanhfast(d[rr]) * vvv;
  }
  #pragma unroll
  for (int m = 1; m < 16; m <<= 1) {
    #pragma unroll
    for (int rr = 0; rr < 4; ++rr) part[rr] += __shfl_xor(part[rr], m, 64);
  }
  if ((lane & 15) == 0) {
    #pragma unroll
    for (int rr = 0; rr < 4; ++rr) {
      int b = q*16 + ((lane>>4)&3)*4 + rr;
      attbuf[(size_t)b*S_ + s] = part[rr];
    }
  }
}

// ---------------- softmax over s per b ----------------
__global__ void __launch_bounds__(256) k_att2(const float* __restrict__ attbuf,
                                              float* __restrict__ wbuf){
  const int b = blockIdx.x, tid = threadIdx.x;
  __shared__ float sm[4];
  float v0 = attbuf[(size_t)b*S_ + tid];
  float v1 = attbuf[(size_t)b*S_ + 256 + tid];
  float m = fmaxf(v0, v1);
  #pragma unroll
  for (int o = 1; o < 64; o <<= 1) m = fmaxf(m, __shfl_xor(m, o, 64));
  if ((tid & 63) == 0) sm[tid >> 6] = m;
  __syncthreads();
  m = fmaxf(fmaxf(sm[0], sm[1]), fmaxf(sm[2], sm[3]));
  __syncthreads();
  float e0 = __expf(v0 - m), e1 = __expf(v1 - m);
  float su = e0 + e1;
  #pragma unroll
  for (int o = 1; o < 64; o <<= 1) su += __shfl_xor(su, o, 64);
  if ((tid & 63) == 0) sm[tid >> 6] = su;
  __syncthreads();
  su = (sm[0] + sm[1]) + (sm[2] + sm[3]);
  wbuf[(size_t)b*S_ + tid]       = e0 / su;
  wbuf[(size_t)b*S_ + 256 + tid] = e1 / su;
}

// ---------------- weighted sum: out[b][2H] ----------------
__global__ void __launch_bounds__(256) k_att3(const unsigned int* __restrict__ hpk,
                                              const float* __restrict__ wbuf,
                                              float* __restrict__ out){
  const int bid = blockIdx.x;              // 128
  const int dir = bid >> 6, q = (bid >> 4) & 3, kt = bid & 15;
  const int tid = threadIdx.x;
  __shared__ float wl[16*512];
  for (int i = tid; i < 16*512; i += 256) {
    int bb = i >> 9, ss = i & 511;
    wl[i] = wbuf[(size_t)(q*16 + bb)*S_ + ss];
  }
  __syncthreads();
  const int l2 = tid >> 2, jj = (tid & 3)*2;
  const int b_l = l2 & 15;
  float acc0 = 0.f, acc1 = 0.f;
  for (int t = 0; t < S_; ++t) {
    const unsigned int* hb = hpk + ((((size_t)dir*S_ + t)*4 + q) << 13) + kt*512 + l2*8 + jj;
    uint2 u = *(const uint2*)hb;
    float w = wl[b_l*512 + t];
    acc0 += w * (bf2f((unsigned short)(u.x >> 16)) + bf2f((unsigned short)(u.x & 0xffffu)));
    acc1 += w * (bf2f((unsigned short)(u.y >> 16)) + bf2f((unsigned short)(u.y & 0xffffu)));
  }
  int k = kt*32 + ((l2 >> 4) & 3)*8 + jj;
  float* o = out + (size_t)(q*16 + b_l)*1024 + dir*512 + k;
  o[0] = acc0;
  o[1] = acc1;
}

// ---------------- launcher ----------------
extern "C" void kernel_launch(void* const* d_in, const int* in_sizes, int n_in,
                              void* d_out, int out_size, void* d_ws, size_t ws_size,
                              hipStream_t stream) {
  const float* x     = (const float*)d_in[0];
  const float* fWih  = (const float*)d_in[1];
  const float* fWhh  = (const float*)d_in[2];
  const float* fbih  = (const float*)d_in[3];
  const float* fbhh  = (const float*)d_in[4];
  const float* bWih  = (const float*)d_in[5];
  const float* bWhh  = (const float*)d_in[6];
  const float* bbih  = (const float*)d_in[7];
  const float* bbhh  = (const float*)d_in[8];
  const float* attW  = (const float*)d_in[9];
  const float* attv  = (const float*)d_in[10];
  float* out = (float*)d_out;

  char* ws = (char*)d_ws;
  const size_t OFF_HPK  = 0;
  const size_t OFF_XHI  = 134217728;            // 128 MB
  const size_t OFF_XLO  = OFF_XHI + 16777216;
  const size_t OFF_WHI  = OFF_XLO + 16777216;   // 160 MB
  const size_t OFF_WLO  = OFF_WHI + 8388608;
  const size_t OFF_AWHI = OFF_WLO + 8388608;    // 176 MB
  const size_t OFF_AWLO = OFF_AWHI + 131072;
  const size_t OFF_ATTB = OFF_AWLO + 131072;
  const size_t OFF_WBUF = OFF_ATTB + 131072;
  const size_t OFF_HX   = OFF_WBUF + 131072;    // 512 KB rotating exchange

  unsigned int*   hpk  = (unsigned int*)(ws + OFF_HPK);
  unsigned short* xhi  = (unsigned short*)(ws + OFF_XHI);
  unsigned short* xlo  = (unsigned short*)(ws + OFF_XLO);
  unsigned short* whi  = (unsigned short*)(ws + OFF_WHI);
  unsigned short* wlo  = (unsigned short*)(ws + OFF_WLO);
  unsigned short* awhi = (unsigned short*)(ws + OFF_AWHI);
  unsigned short* awlo = (unsigned short*)(ws + OFF_AWLO);
  float*          attb = (float*)(ws + OFF_ATTB);
  float*          wbuf = (float*)(ws + OFF_WBUF);
  unsigned int*   hx   = (unsigned int*)(ws + OFF_HX);

  // reset the exchange to the impossible-bf16 sentinel each launch (kills replay staleness)
  hipMemsetAsync(hx, 0xFF, 524288, stream);

  k_xfrag <<<4096, 256, 0, stream>>>(x, xhi, xlo);
  k_wfrag <<<2048, 256, 0, stream>>>(fWih, bWih, whi, wlo);
  k_awfrag<<<32,   256, 0, stream>>>(attW, awhi, awlo);

  const int LDS_BYTES = 151552;   // 80K Whh + 32K h-stage + 4K gbuf + 32K xbuf
  hipFuncSetAttribute((const void*)k_lstm, hipFuncAttributeMaxDynamicSharedMemorySize, LDS_BYTES);
  k_lstm<<<256, 256, LDS_BYTES, stream>>>(fWhh, bWhh, fbih, fbhh, bbih, bbhh,
                                          hpk, hx, xhi, xlo, whi, wlo);

  k_att1<<<512, 256, 0, stream>>>(hpk, awhi, awlo, attv, attb);
  k_att2<<<64,  256, 0, stream>>>(attb, wbuf);
  k_att3<<<128, 256, 0, stream>>>(hpk, wbuf, out);
}

// Round 14
// 1882.949 us; speedup vs baseline: 1.1565x; 1.1565x over previous
//
#include <hip/hip_runtime.h>

#define B_ 64
#define S_ 512
#define D_ 256
#define H_ 512

typedef __attribute__((ext_vector_type(8))) short bfx8;
typedef __attribute__((ext_vector_type(4))) float f32x4;

#define MFMA16(a,b,c) __builtin_amdgcn_mfma_f32_16x16x32_bf16((a),(b),(c),0,0,0)
#define AL(p)  __hip_atomic_load((p), __ATOMIC_RELAXED, __HIP_MEMORY_SCOPE_AGENT)

__device__ __forceinline__ unsigned short f2bf(float x){
  union { float f; unsigned int u; } v; v.f = x;
  unsigned int r = v.u + 0x7fffu + ((v.u >> 16) & 1u);
  return (unsigned short)(r >> 16);
}
__device__ __forceinline__ float bf2f(unsigned short b){
  union { unsigned int u; float f; } v; v.u = ((unsigned int)b) << 16; return v.f;
}
__device__ __forceinline__ float sigm(float x){ return 1.f/(1.f + __expf(-x)); }
__device__ __forceinline__ float tanhfast(float x){
  float xc = fminf(fmaxf(x, -15.f), 15.f);
  float e = __expf(2.f * xc);
  return (e - 1.f) / (e + 1.f);
}
__device__ __forceinline__ void unpack8(uint4 a, uint4 b, bfx8& hi, bfx8& lo){
  hi[0]=(short)(a.x>>16); lo[0]=(short)(a.x&0xffffu);
  hi[1]=(short)(a.y>>16); lo[1]=(short)(a.y&0xffffu);
  hi[2]=(short)(a.z>>16); lo[2]=(short)(a.z&0xffffu);
  hi[3]=(short)(a.w>>16); lo[3]=(short)(a.w&0xffffu);
  hi[4]=(short)(b.x>>16); lo[4]=(short)(b.x&0xffffu);
  hi[5]=(short)(b.y>>16); lo[5]=(short)(b.y&0xffffu);
  hi[6]=(short)(b.z>>16); lo[6]=(short)(b.z&0xffffu);
  hi[7]=(short)(b.w>>16); lo[7]=(short)(b.w&0xffffu);
}
__device__ __forceinline__ void cvt8(const float* vv, bfx8& hi, bfx8& lo){
  #pragma unroll
  for (int j = 0; j < 8; ++j) {
    unsigned short h = f2bf(vv[j]);
    hi[j] = (short)h;
    lo[j] = (short)f2bf(vv[j] - bf2f(h));
  }
}

// ---------------- prep: x fragments [t][q][kt(8)][lane(64)][8] hi/lo ----------------
__global__ void __launch_bounds__(256) k_xfrag(const float* __restrict__ x,
                                               unsigned short* __restrict__ xhi,
                                               unsigned short* __restrict__ xlo){
  int idx = blockIdx.x*256 + threadIdx.x;            // 2^20 threads
  int lane = idx & 63, kt = (idx>>6)&7, q = (idx>>9)&3, t = idx>>11;
  int b = q*16 + (lane&15);
  int k0 = kt*32 + ((lane>>4)&3)*8;
  const float4* p = (const float4*)(x + ((size_t)b*S_ + t)*D_ + k0);
  float4 v0 = p[0], v1 = p[1];
  float vv[8] = {v0.x,v0.y,v0.z,v0.w,v1.x,v1.y,v1.z,v1.w};
  bfx8 hi, lo; cvt8(vv, hi, lo);
  *(bfx8*)(xhi + (size_t)idx*8) = hi;
  *(bfx8*)(xlo + (size_t)idx*8) = lo;
}

// ---------------- prep: Wih fragments [dir][q][r(32)][kt(8)][nt(4)][lane(64)][8] ----------------
__global__ void __launch_bounds__(256) k_wfrag(const float* __restrict__ fWih,
                                               const float* __restrict__ bWih,
                                               unsigned short* __restrict__ whi,
                                               unsigned short* __restrict__ wlo){
  int idx = blockIdx.x*256 + threadIdx.x;            // 2^19 threads
  int lane = idx & 63, nt = (idx>>6)&3, kt = (idx>>8)&7, r = (idx>>11)&31, dir = (idx>>18)&1;
  int row = nt*512 + r*16 + (lane&15);
  int k0 = kt*32 + ((lane>>4)&3)*8;
  const float* W = dir ? bWih : fWih;
  const float4* p = (const float4*)(W + (size_t)row*D_ + k0);
  float4 v0 = p[0], v1 = p[1];
  float vv[8] = {v0.x,v0.y,v0.z,v0.w,v1.x,v1.y,v1.z,v1.w};
  bfx8 hi, lo; cvt8(vv, hi, lo);
  *(bfx8*)(whi + (size_t)idx*8) = hi;
  *(bfx8*)(wlo + (size_t)idx*8) = lo;
}

// ---------------- prep: att_W fragments [nt(4)][kt(32)][lane(64)][8] ----------------
__global__ void __launch_bounds__(256) k_awfrag(const float* __restrict__ attW,
                                                unsigned short* __restrict__ awhi,
                                                unsigned short* __restrict__ awlo){
  int idx = blockIdx.x*256 + threadIdx.x;            // 8192 threads
  int lane = idx & 63, kt = (idx>>6)&31, nt = idx>>11;
  int n = nt*16 + (lane&15);
  int k0 = kt*32 + ((lane>>4)&3)*8;
  const float4* p = (const float4*)(attW + (size_t)n*1024 + k0);
  float4 v0 = p[0], v1 = p[1];
  float vv[8] = {v0.x,v0.y,v0.z,v0.w,v1.x,v1.y,v1.z,v1.w};
  bfx8 hi, lo; cvt8(vv, hi, lo);
  *(bfx8*)(awhi + (size_t)idx*8) = hi;
  *(bfx8*)(awlo + (size_t)idx*8) = lo;
}

// ---------------- main recurrence: 256 WGs = 8 groups(dir x quarter) x 32 col-WGs ----------------
// R12 structure (rotating hot exchange + x software pipeline + per-wave digest post) with:
//  (1) bulk h-read via PLAIN global_load_dwordx4 sc0 sc1 (bypass L1+L2, served at LLC):
//      coalescable line requests instead of 4096 per-lane atomic ops per WG per step.
//      Correctness: digest gate + per-wave vmcnt(0)-before-post means data is at the LLC
//      before any read; sc0 sc1 loads cannot hit a stale L1/L2 copy.
//  (2) history hpk store moved AFTER the digest post (off the drain path).
__global__ void __launch_bounds__(256,1) k_lstm(
    const float* __restrict__ fWhh, const float* __restrict__ bWhh,
    const float* __restrict__ fbih, const float* __restrict__ fbhh,
    const float* __restrict__ bbih, const float* __restrict__ bbhh,
    unsigned int* __restrict__ hpk,          // 128 MB history (plain stores, attention input)
    unsigned int* __restrict__ hx,           // 512 KB rotating exchange
    const unsigned short* __restrict__ xhi, const unsigned short* __restrict__ xlo,
    const unsigned short* __restrict__ whi, const unsigned short* __restrict__ wlo,
    int* __restrict__ dg)
{
  extern __shared__ char smem[];
  unsigned short* shh   = (unsigned short*)smem;            // Whh hi frags kt0..9 = 40960 B
  unsigned short* shl   = shh + 20480;                      // Whh lo frags kt0..9 = 40960 B
  unsigned short* sh_hi = (unsigned short*)(smem + 81920);  // staged h hi [kt16][lane64][8] = 16 KB
  unsigned short* sh_lo = sh_hi + 8192;                     // staged h lo = 16 KB
  float* gbuf = (float*)(smem + 114688);                    // gate exchange [4][16][16] = 4 KB
  char*  xbuf = smem + 118784;                              // x frags ping-pong 2 x 16 KB

  const int tid = threadIdx.x, bid = blockIdx.x;
  const int g = bid & 7, r = bid >> 3;
  const int dir = g >> 2, q = g & 3;
  const int wv = tid >> 6, lane = tid & 63;
  const float* Whh = dir ? bWhh : fWhh;

  // stage Whh slice: kt 0..9 -> LDS fragments; kt 10..15 -> registers
  bfx8 rbh[6], rbl[6];
  #pragma unroll
  for (int i = 0; i < 16; ++i) {
    int fl = tid & 63, fnt = (tid>>6)&3;
    int row = fnt*512 + r*16 + (fl&15);
    int k0 = i*32 + ((fl>>4)&3)*8;
    const float4* p = (const float4*)(Whh + (size_t)row*H_ + k0);
    float4 v0 = p[0], v1 = p[1];
    float vv[8] = {v0.x,v0.y,v0.z,v0.w,v1.x,v1.y,v1.z,v1.w};
    bfx8 hi, lo; cvt8(vv, hi, lo);
    if (i < 10) {
      *(bfx8*)(shh + (size_t)((i*4+fnt)*64+fl)*8) = hi;
      *(bfx8*)(shl + (size_t)((i*4+fnt)*64+fl)*8) = lo;
    } else { rbh[i-10] = hi; rbl[i-10] = lo; }
  }

  // Wih fragments -> registers (constant across steps)
  bfx8 wrh[8], wrl[8];
  {
    const size_t wb = (((size_t)(dir*4+q)*32 + r)*32 + wv)*64;
    #pragma unroll
    for (int kt = 0; kt < 8; ++kt) {
      wrh[kt] = *(const bfx8*)(whi + (wb + kt*256 + lane)*8);
      wrl[kt] = *(const bfx8*)(wlo + (wb + kt*256 + lane)*8);
    }
  }

  const int b_l = tid >> 4, cc = tid & 15;
  const int jcol = r*16 + cc;
  const float* bih = dir ? bbih : fbih;
  const float* bhh = dir ? bbhh : fbhh;
  float bias[4];
  #pragma unroll
  for (int gt = 0; gt < 4; ++gt) bias[gt] = bih[gt*512 + jcol] + bhh[gt*512 + jcol];
  float cst = 0.f;
  const int hkt   = jcol >> 5;
  const int hlane = ((jcol>>3)&3)*16 + b_l;
  const int hj    = jcol & 7;
  const int d0    = g*128 + lane*2;        // each lane polls 2 of the 128 wave-epoch words
  const int kts   = tid >> 7;              // bulk-read half-split
  const int tl    = tid & 127;

  { // prologue: preload step-0 x block into xbuf[0]
    const int t0 = dir ? (S_-1) : 0;
    const char* hsrc = (const char*)(xhi + (((size_t)t0*4+q) << 12));
    const char* lsrc = (const char*)(xlo + (((size_t)t0*4+q) << 12));
    *(uint4*)(xbuf + tid*16)          = *(const uint4*)(hsrc + tid*16);
    *(uint4*)(xbuf + 4096 + tid*16)   = *(const uint4*)(hsrc + 4096 + tid*16);
    *(uint4*)(xbuf + 8192 + tid*16)   = *(const uint4*)(lsrc + tid*16);
    *(uint4*)(xbuf + 12288 + tid*16)  = *(const uint4*)(lsrc + 4096 + tid*16);
  }
  __syncthreads();

  for (int ti = 0; ti < S_; ++ti) {
    const int t = dir ? (S_-1-ti) : ti;
    char* xb  = xbuf + ((ti)&1)*16384;
    char* xbn = xbuf + ((ti+1)&1)*16384;
    f32x4 a0 = {0.f,0.f,0.f,0.f}, a1 = a0, a2 = a0, a3 = a0, a4 = a0, a5 = a0;

    // ---- issue next step's x-block loads (land under the rendezvous) ----
    uint4 xr0, xr1, xr2, xr3;
    const bool pf = (ti + 1 < S_);
    if (pf) {
      const int tn = dir ? (S_-1-(ti+1)) : (ti+1);
      const char* hsrc = (const char*)(xhi + (((size_t)tn*4+q) << 12));
      const char* lsrc = (const char*)(xlo + (((size_t)tn*4+q) << 12));
      xr0 = *(const uint4*)(hsrc + tid*16);
      xr1 = *(const uint4*)(hsrc + 4096 + tid*16);
      xr2 = *(const uint4*)(lsrc + tid*16);
      xr3 = *(const uint4*)(lsrc + 4096 + tid*16);
    }

    { // input projection from LDS (h-independent)
      const unsigned short* xh = (const unsigned short*)xb;
      const unsigned short* xl = (const unsigned short*)(xb + 8192);
      #pragma unroll
      for (int kt = 0; kt < 8; ++kt) {
        bfx8 x0 = *(const bfx8*)(xh + (size_t)(kt*64+lane)*8);
        bfx8 x1 = *(const bfx8*)(xl + (size_t)(kt*64+lane)*8);
        if (kt & 1) {
          a3 = MFMA16(x0, wrh[kt], a3); a4 = MFMA16(x0, wrl[kt], a4); a5 = MFMA16(x1, wrh[kt], a5);
        } else {
          a0 = MFMA16(x0, wrh[kt], a0); a1 = MFMA16(x0, wrl[kt], a1); a2 = MFMA16(x1, wrh[kt], a2);
        }
      }
    }

    if (ti > 0) {
      // ---- digest wait: 128 wave-epoch words per group, 2 per lane ----
      for (;;) {
        int v0 = AL(dg + d0), v1 = AL(dg + d0 + 1);
        if (__all((v0 >= ti) & (v1 >= ti))) break;
      }
      asm volatile("" ::: "memory");
      // ---- bulk h-load: coalesced dwordx4 with sc0 sc1 (L1/L2 bypass, LLC-served) ----
      const char* sb =
          (const char*)(hx + ((((size_t)(dir*4 + q))*2 + ((ti-1)&1)) << 13));
      const char* A0 = sb + (size_t)(0*4096 + kts*2048) + tl*16;
      const char* A1 = sb + (size_t)(1*4096 + kts*2048) + tl*16;
      const char* A2 = sb + (size_t)(2*4096 + kts*2048) + tl*16;
      const char* A3 = sb + (size_t)(3*4096 + kts*2048) + tl*16;
      const char* A4 = sb + (size_t)(4*4096 + kts*2048) + tl*16;
      const char* A5 = sb + (size_t)(5*4096 + kts*2048) + tl*16;
      const char* A6 = sb + (size_t)(6*4096 + kts*2048) + tl*16;
      const char* A7 = sb + (size_t)(7*4096 + kts*2048) + tl*16;
      uint4 qv0, qv1, qv2, qv3, qv4, qv5, qv6, qv7;
      asm volatile(
        "global_load_dwordx4 %0, %8, off sc0 sc1\n\t"
        "global_load_dwordx4 %1, %9, off sc0 sc1\n\t"
        "global_load_dwordx4 %2, %10, off sc0 sc1\n\t"
        "global_load_dwordx4 %3, %11, off sc0 sc1\n\t"
        "global_load_dwordx4 %4, %12, off sc0 sc1\n\t"
        "global_load_dwordx4 %5, %13, off sc0 sc1\n\t"
        "global_load_dwordx4 %6, %14, off sc0 sc1\n\t"
        "global_load_dwordx4 %7, %15, off sc0 sc1\n\t"
        "s_waitcnt vmcnt(0)"
        : "=&v"(qv0), "=&v"(qv1), "=&v"(qv2), "=&v"(qv3),
          "=&v"(qv4), "=&v"(qv5), "=&v"(qv6), "=&v"(qv7)
        : "v"(A0), "v"(A1), "v"(A2), "v"(A3), "v"(A4), "v"(A5), "v"(A6), "v"(A7)
        : "memory");
      __builtin_amdgcn_sched_barrier(0);
      // ---- stage to LDS (hi/lo planes) ----
      unsigned int* shiu = (unsigned int*)sh_hi;
      unsigned int* slou = (unsigned int*)sh_lo;
      uint4 qa[8] = {qv0, qv1, qv2, qv3, qv4, qv5, qv6, qv7};
      #pragma unroll
      for (int j = 0; j < 8; ++j) {
        const int kt = 2*j + kts;
        uint2 hw, lw;
        hw.x = (qa[j].x >> 16)     | (qa[j].y & 0xFFFF0000u);
        lw.x = (qa[j].x & 0xFFFFu) | (qa[j].y << 16);
        hw.y = (qa[j].z >> 16)     | (qa[j].w & 0xFFFF0000u);
        lw.y = (qa[j].z & 0xFFFFu) | (qa[j].w << 16);
        *(uint2*)(shiu + kt*256 + tl*2) = hw;
        *(uint2*)(slou + kt*256 + tl*2) = lw;
      }
    }
    // ---- write the prefetched x-block into the other ping-pong half ----
    if (pf) {
      *(uint4*)(xbn + tid*16)         = xr0;
      *(uint4*)(xbn + 4096 + tid*16)  = xr1;
      *(uint4*)(xbn + 8192 + tid*16)  = xr2;
      *(uint4*)(xbn + 12288 + tid*16) = xr3;
    }
    __syncthreads();               // barB: stage + xbuf visible
    if (ti > 0) {
      #pragma unroll
      for (int kt = 0; kt < 16; ++kt) {
        bfx8 ah = *(const bfx8*)(sh_hi + kt*512 + lane*8);
        bfx8 al = *(const bfx8*)(sh_lo + kt*512 + lane*8);
        bfx8 bh, bl;
        if (kt < 10) {
          bh = *(const bfx8*)(shh + (size_t)((kt*4+wv)*64 + lane)*8);
          bl = *(const bfx8*)(shl + (size_t)((kt*4+wv)*64 + lane)*8);
        } else { bh = rbh[kt-10]; bl = rbl[kt-10]; }
        if (kt & 1) {
          a3 = MFMA16(ah, bh, a3); a4 = MFMA16(ah, bl, a4); a5 = MFMA16(al, bh, a5);
        } else {
          a0 = MFMA16(ah, bh, a0); a1 = MFMA16(ah, bl, a1); a2 = MFMA16(al, bh, a2);
        }
      }
    }

    f32x4 gate = (a0 + a1) + (a2 + a3) + (a4 + a5);
    #pragma unroll
    for (int rr = 0; rr < 4; ++rr)
      gbuf[wv*256 + (((lane>>4)&3)*4+rr)*16 + (lane&15)] = gate[rr];
    __syncthreads();               // barD: gbuf visible
    unsigned int pk;
    size_t hoff;
    {
      float gi = gbuf[0*256 + b_l*16 + cc] + bias[0];
      float gf = gbuf[1*256 + b_l*16 + cc] + bias[1];
      float gg = gbuf[2*256 + b_l*16 + cc] + bias[2];
      float go = gbuf[3*256 + b_l*16 + cc] + bias[3];
      float is = sigm(gi), fs = sigm(gf), gs = tanhfast(gg), os = sigm(go);
      cst = fs*cst + is*gs;
      float hv = os * tanhfast(cst);
      unsigned short hh = f2bf(hv);
      unsigned short hl = f2bf(hv - bf2f(hh));
      pk = (((unsigned int)hh) << 16) | (unsigned int)hl;
      hoff = (size_t)hkt*512 + hlane*8 + hj;
      __hip_atomic_store(hx + ((((size_t)(dir*4 + q))*2 + (ti&1)) << 13) + hoff, pk,
                         __ATOMIC_RELAXED, __HIP_MEMORY_SCOPE_AGENT);      // exchange first
    }
    // ---- per-wave post: own exchange store acked, then lane0 posts this wave's epoch ----
    asm volatile("s_waitcnt vmcnt(0)" ::: "memory");
    if (lane == 0)
      __hip_atomic_store(dg + g*128 + r*4 + wv, ti + 1, __ATOMIC_RELAXED, __HIP_MEMORY_SCOPE_AGENT);
    // history store AFTER the post: off the rendezvous critical path (attention reads it
    // only after this kernel ends; ordered by the next step's vmcnt(0) / kernel end).
    hpk[((((size_t)dir*S_ + t)*4 + q) << 13) + hoff] = pk;
  }
}

// ---------------- attention scores: one WG per s ----------------
__global__ void __launch_bounds__(256) k_att1(const unsigned int* __restrict__ hpk,
                                              const unsigned short* __restrict__ awhi,
                                              const unsigned short* __restrict__ awlo,
                                              const float* __restrict__ attv,
                                              float* __restrict__ attbuf){
  const int s = blockIdx.x;
  const int tid = threadIdx.x, wv = tid >> 6, lane = tid & 63;
  const int q = wv;
  f32x4 z = {0.f,0.f,0.f,0.f};
  f32x4 acc[4][3];
  #pragma unroll
  for (int nt = 0; nt < 4; ++nt) { acc[nt][0] = z; acc[nt][1] = z; acc[nt][2] = z; }
  for (int kt = 0; kt < 32; ++kt) {
    int dir = kt >> 4, ktt = kt & 15;
    const unsigned int* hb = hpk + ((((size_t)dir*S_ + s)*4 + q) << 13) + ktt*512 + lane*8;
    uint4 u0 = *(const uint4*)hb, u1 = *(const uint4*)(hb + 4);
    bfx8 ah, al; unpack8(u0, u1, ah, al);
    #pragma unroll
    for (int nt = 0; nt < 4; ++nt) {
      bfx8 bh = *(const bfx8*)(awhi + (size_t)((nt*32+kt)*64+lane)*8);
      bfx8 bl = *(const bfx8*)(awlo + (size_t)((nt*32+kt)*64+lane)*8);
      acc[nt][0] = MFMA16(ah, bh, acc[nt][0]);
      acc[nt][1] = MFMA16(ah, bl, acc[nt][1]);
      acc[nt][2] = MFMA16(al, bh, acc[nt][2]);
    }
  }
  float part[4] = {0.f,0.f,0.f,0.f};
  #pragma unroll
  for (int nt = 0; nt < 4; ++nt) {
    f32x4 d = (acc[nt][0] + acc[nt][1]) + acc[nt][2];
    float vvv = attv[nt*16 + (lane&15)];
    #pragma unroll
    for (int rr = 0; rr < 4; ++rr) part[rr] += tanhfast(d[rr]) * vvv;
  }
  #pragma unroll
  for (int m = 1; m < 16; m <<= 1) {
    #pragma unroll
    for (int rr = 0; rr < 4; ++rr) part[rr] += __shfl_xor(part[rr], m, 64);
  }
  if ((lane & 15) == 0) {
    #pragma unroll
    for (int rr = 0; rr < 4; ++rr) {
      int b = q*16 + ((lane>>4)&3)*4 + rr;
      attbuf[(size_t)b*S_ + s] = part[rr];
    }
  }
}

// ---------------- softmax over s per b ----------------
__global__ void __launch_bounds__(256) k_att2(const float* __restrict__ attbuf,
                                              float* __restrict__ wbuf){
  const int b = blockIdx.x, tid = threadIdx.x;
  __shared__ float sm[4];
  float v0 = attbuf[(size_t)b*S_ + tid];
  float v1 = attbuf[(size_t)b*S_ + 256 + tid];
  float m = fmaxf(v0, v1);
  #pragma unroll
  for (int o = 1; o < 64; o <<= 1) m = fmaxf(m, __shfl_xor(m, o, 64));
  if ((tid & 63) == 0) sm[tid >> 6] = m;
  __syncthreads();
  m = fmaxf(fmaxf(sm[0], sm[1]), fmaxf(sm[2], sm[3]));
  __syncthreads();
  float e0 = __expf(v0 - m), e1 = __expf(v1 - m);
  float su = e0 + e1;
  #pragma unroll
  for (int o = 1; o < 64; o <<= 1) su += __shfl_xor(su, o, 64);
  if ((tid & 63) == 0) sm[tid >> 6] = su;
  __syncthreads();
  su = (sm[0] + sm[1]) + (sm[2] + sm[3]);
  wbuf[(size_t)b*S_ + tid]       = e0 / su;
  wbuf[(size_t)b*S_ + 256 + tid] = e1 / su;
}

// ---------------- weighted sum: out[b][2H] ----------------
__global__ void __launch_bounds__(256) k_att3(const unsigned int* __restrict__ hpk,
                                              const float* __restrict__ wbuf,
                                              float* __restrict__ out){
  const int bid = blockIdx.x;              // 128
  const int dir = bid >> 6, q = (bid >> 4) & 3, kt = bid & 15;
  const int tid = threadIdx.x;
  __shared__ float wl[16*512];
  for (int i = tid; i < 16*512; i += 256) {
    int bb = i >> 9, ss = i & 511;
    wl[i] = wbuf[(size_t)(q*16 + bb)*S_ + ss];
  }
  __syncthreads();
  const int l2 = tid >> 2, jj = (tid & 3)*2;
  const int b_l = l2 & 15;
  float acc0 = 0.f, acc1 = 0.f;
  for (int t = 0; t < S_; ++t) {
    const unsigned int* hb = hpk + ((((size_t)dir*S_ + t)*4 + q) << 13) + kt*512 + l2*8 + jj;
    uint2 u = *(const uint2*)hb;
    float w = wl[b_l*512 + t];
    acc0 += w * (bf2f((unsigned short)(u.x >> 16)) + bf2f((unsigned short)(u.x & 0xffffu)));
    acc1 += w * (bf2f((unsigned short)(u.y >> 16)) + bf2f((unsigned short)(u.y & 0xffffu)));
  }
  int k = kt*32 + ((l2 >> 4) & 3)*8 + jj;
  float* o = out + (size_t)(q*16 + b_l)*1024 + dir*512 + k;
  o[0] = acc0;
  o[1] = acc1;
}

// ---------------- launcher ----------------
extern "C" void kernel_launch(void* const* d_in, const int* in_sizes, int n_in,
                              void* d_out, int out_size, void* d_ws, size_t ws_size,
                              hipStream_t stream) {
  const float* x     = (const float*)d_in[0];
  const float* fWih  = (const float*)d_in[1];
  const float* fWhh  = (const float*)d_in[2];
  const float* fbih  = (const float*)d_in[3];
  const float* fbhh  = (const float*)d_in[4];
  const float* bWih  = (const float*)d_in[5];
  const float* bWhh  = (const float*)d_in[6];
  const float* bbih  = (const float*)d_in[7];
  const float* bbhh  = (const float*)d_in[8];
  const float* attW  = (const float*)d_in[9];
  const float* attv  = (const float*)d_in[10];
  float* out = (float*)d_out;

  char* ws = (char*)d_ws;
  const size_t OFF_HPK  = 0;
  const size_t OFF_XHI  = 134217728;            // 128 MB
  const size_t OFF_XLO  = OFF_XHI + 16777216;
  const size_t OFF_WHI  = OFF_XLO + 16777216;   // 160 MB
  const size_t OFF_WLO  = OFF_WHI + 8388608;
  const size_t OFF_AWHI = OFF_WLO + 8388608;    // 176 MB
  const size_t OFF_AWLO = OFF_AWHI + 131072;
  const size_t OFF_ATTB = OFF_AWLO + 131072;
  const size_t OFF_WBUF = OFF_ATTB + 131072;
  const size_t OFF_DG   = OFF_WBUF + 131072;
  const size_t OFF_HX   = OFF_DG + 4096;        // 512 KB rotating exchange

  unsigned int*   hpk  = (unsigned int*)(ws + OFF_HPK);
  unsigned short* xhi  = (unsigned short*)(ws + OFF_XHI);
  unsigned short* xlo  = (unsigned short*)(ws + OFF_XLO);
  unsigned short* whi  = (unsigned short*)(ws + OFF_WHI);
  unsigned short* wlo  = (unsigned short*)(ws + OFF_WLO);
  unsigned short* awhi = (unsigned short*)(ws + OFF_AWHI);
  unsigned short* awlo = (unsigned short*)(ws + OFF_AWLO);
  float*          attb = (float*)(ws + OFF_ATTB);
  float*          wbuf = (float*)(ws + OFF_WBUF);
  int*            dg   = (int*)(ws + OFF_DG);
  unsigned int*   hx   = (unsigned int*)(ws + OFF_HX);

  // zero the epoch digests (128 wave-words x 8 groups = 4 KB)
  hipMemsetAsync(dg, 0, 4096, stream);

  k_xfrag <<<4096, 256, 0, stream>>>(x, xhi, xlo);
  k_wfrag <<<2048, 256, 0, stream>>>(fWih, bWih, whi, wlo);
  k_awfrag<<<32,   256, 0, stream>>>(attW, awhi, awlo);

  const int LDS_BYTES = 151552;   // 80K Whh + 32K h-stage + 4K gbuf + 32K xbuf
  hipFuncSetAttribute((const void*)k_lstm, hipFuncAttributeMaxDynamicSharedMemorySize, LDS_BYTES);
  k_lstm<<<256, 256, LDS_BYTES, stream>>>(fWhh, bWhh, fbih, fbhh, bbih, bbhh,
                                          hpk, hx, xhi, xlo, whi, wlo, dg);

  k_att1<<<512, 256, 0, stream>>>(hpk, awhi, awlo, attv, attb);
  k_att2<<<64,  256, 0, stream>>>(attb, wbuf);
  k_att3<<<128, 256, 0, stream>>>(hpk, wbuf, out);
}